// Round 6
// baseline (246.461 us; speedup 1.0000x reference)
//
#include <hip/hip_runtime.h>
#include <math.h>

// Problem constants
#define B_   32
#define T_   256
#define DV_  1024
#define DJ_  512
#define L_   20
#define T0_  127
#define T1_  62
#define T2_  30
#define TP_  219          // 127+62+30
#define LAM_ 4.0f
#define MARGIN_ 0.1f

typedef __attribute__((ext_vector_type(8))) short short8;
typedef __attribute__((ext_vector_type(4))) float f32x4;

static __device__ __forceinline__ unsigned short f2bf(float f) {
  union { float f; unsigned u; } v; v.f = f;
  unsigned r = v.u + 0x7fff + ((v.u >> 16) & 1);   // round-to-nearest-even
  return (unsigned short)(r >> 16);
}

struct ushort4_t { unsigned short x, y, z, w; };

#define GLOAD_LDS16(gp, lp)                                                      \
  __builtin_amdgcn_global_load_lds(                                              \
      (const __attribute__((address_space(1))) void*)(gp),                       \
      (__attribute__((address_space(3))) void*)(lp), 16, 0, 0)

// ---------------------------------------------------------------------------
// Weight reorder+cast, coalesced: thread = (co,ci), float4 read of 4 taps,
// 4 coalesced ushort stores at stride Cin.  pw = straight cast.
// ---------------------------------------------------------------------------
__global__ void reorder_all_k(const float* __restrict__ c0w, const float* __restrict__ c1w,
                              const float* __restrict__ c2w, const float* __restrict__ pww,
                              unsigned short* __restrict__ W0, unsigned short* __restrict__ W1,
                              unsigned short* __restrict__ W2, unsigned short* __restrict__ Wp) {
  int bid = blockIdx.x;
  if (bid < 2048) {            // conv0: 512*1024 (co,ci) pairs
    int idx = bid * 256 + threadIdx.x;
    int co = idx >> 10, ci = idx & 1023;
    float4 w = *reinterpret_cast<const float4*>(c0w + (size_t)idx * 4);
    unsigned short* d = W0 + (size_t)co * 4096 + ci;
    d[0] = f2bf(w.x); d[1024] = f2bf(w.y); d[2048] = f2bf(w.z); d[3072] = f2bf(w.w);
  } else if (bid < 3072) {     // conv1: 512*512
    int idx = (bid - 2048) * 256 + threadIdx.x;
    int co = idx >> 9, ci = idx & 511;
    float4 w = *reinterpret_cast<const float4*>(c1w + (size_t)idx * 4);
    unsigned short* d = W1 + (size_t)co * 2048 + ci;
    d[0] = f2bf(w.x); d[512] = f2bf(w.y); d[1024] = f2bf(w.z); d[1536] = f2bf(w.w);
  } else if (bid < 4096) {     // conv2: 512*512
    int idx = (bid - 3072) * 256 + threadIdx.x;
    int co = idx >> 9, ci = idx & 511;
    float4 w = *reinterpret_cast<const float4*>(c2w + (size_t)idx * 4);
    unsigned short* d = W2 + (size_t)co * 2048 + ci;
    d[0] = f2bf(w.x); d[512] = f2bf(w.y); d[1024] = f2bf(w.z); d[1536] = f2bf(w.w);
  } else {                     // pw: identity cast, 262144 elems / 4
    int idx = (bid - 4096) * 256 + threadIdx.x;
    float4 v = *reinterpret_cast<const float4*>(pww + (size_t)idx * 4);
    ushort4_t h = { f2bf(v.x), f2bf(v.y), f2bf(v.z), f2bf(v.w) };
    reinterpret_cast<ushort4_t*>(Wp)[idx] = h;
  }
}

// ---------------------------------------------------------------------------
// BatchNorm stats, two stage, deterministic, highly parallel.
// ---------------------------------------------------------------------------
__global__ void stats1_k(const float* __restrict__ x, float* __restrict__ part,
                         int C, int rows, int rpg, int cpgShift) {
  int cpg  = 1 << cpgShift;                 // C/4
  int c4   = threadIdx.x & (cpg - 1);
  int rsub = threadIdx.x >> cpgShift;
  int nsub = 256 >> cpgShift;
  int r0 = blockIdx.x * rpg + rsub;
  int r1 = min(blockIdx.x * rpg + rpg, rows);
  float4 s = {0.f,0.f,0.f,0.f}, q = {0.f,0.f,0.f,0.f};
  for (int r = r0; r < r1; r += nsub) {
    float4 v = *reinterpret_cast<const float4*>(&x[(size_t)r * C + c4 * 4]);
    s.x += v.x; s.y += v.y; s.z += v.z; s.w += v.w;
    q.x += v.x*v.x; q.y += v.y*v.y; q.z += v.z*v.z; q.w += v.w*v.w;
  }
  float* ps = part + ((size_t)blockIdx.x * nsub + rsub) * 2 * C;
  reinterpret_cast<float4*>(ps)[c4] = s;
  reinterpret_cast<float4*>(ps + C)[c4] = q;
}

// Stage 2: block handles 128 channels (32 float4); 8 g-stripes; LDS combine.
__global__ void stats2_k(const float* __restrict__ part, float* __restrict__ ms,
                         int C, int ng, float inv_n) {
  __shared__ float4 sS[8][33], sQ[8][33];
  int c4l = threadIdx.x & 31;
  int gs  = threadIdx.x >> 5;
  int c4  = blockIdx.x * 32 + c4l;          // float4 channel index
  float4 s = {0.f,0.f,0.f,0.f}, q = {0.f,0.f,0.f,0.f};
  for (int g = gs; g < ng; g += 8) {
    const float4* ps = reinterpret_cast<const float4*>(part + (size_t)g * 2 * C);
    float4 a = ps[c4];
    float4 b = ps[(C >> 2) + c4];
    s.x += a.x; s.y += a.y; s.z += a.z; s.w += a.w;
    q.x += b.x; q.y += b.y; q.z += b.z; q.w += b.w;
  }
  sS[gs][c4l] = s; sQ[gs][c4l] = q;
  __syncthreads();
  if (gs == 0) {
    float4 S = sS[0][c4l], Q = sQ[0][c4l];
#pragma unroll
    for (int k = 1; k < 8; ++k) {
      float4 a = sS[k][c4l], b = sQ[k][c4l];
      S.x += a.x; S.y += a.y; S.z += a.z; S.w += a.w;
      Q.x += b.x; Q.y += b.y; Q.z += b.z; Q.w += b.w;
    }
    int c = c4 * 4;
    float m0 = S.x * inv_n, m1 = S.y * inv_n, m2 = S.z * inv_n, m3 = S.w * inv_n;
    ms[c+0] = m0; ms[C+c+0] = rsqrtf(Q.x * inv_n - m0*m0 + 1e-5f);
    ms[c+1] = m1; ms[C+c+1] = rsqrtf(Q.y * inv_n - m1*m1 + 1e-5f);
    ms[c+2] = m2; ms[C+c+2] = rsqrtf(Q.z * inv_n - m2*m2 + 1e-5f);
    ms[c+3] = m3; ms[C+c+3] = rsqrtf(Q.w * inv_n - m3*m3 + 1e-5f);
  }
}

// video BN apply + cast to bf16
__global__ void vid_bn_cast_k(const float* __restrict__ video,
                              const float* __restrict__ ms,
                              unsigned short* __restrict__ vbf) {
  int i4 = blockIdx.x * 256 + threadIdx.x;
  float4 v = reinterpret_cast<const float4*>(video)[i4];
  int c = (i4 & 255) * 4;
  v.x = (v.x - ms[c+0]) * ms[1024+c+0];
  v.y = (v.y - ms[c+1]) * ms[1024+c+1];
  v.z = (v.z - ms[c+2]) * ms[1024+c+2];
  v.w = (v.w - ms[c+3]) * ms[1024+c+3];
  ushort4_t h = { f2bf(v.x), f2bf(v.y), f2bf(v.z), f2bf(v.w) };
  reinterpret_cast<ushort4_t*>(vbf)[i4] = h;
}

// ---------------------------------------------------------------------------
// MFMA bf16 GEMM.  BM=128, BN=128, BK=32, 256 thr = 4 waves (2x2), wave tile
// 64x64 (4x4 frags of 16x16x32) -> 2x the MFMA-per-LDS-byte of the 64^2 tile.
// LDS linear, source-side chunk swizzle (same involution on read) -> ~2-way.
// PARTIAL: blockIdx.z = K-split index, writes fp32 dense partial
// [split][m][ldout] (no bias/relu).
// ---------------------------------------------------------------------------
template<bool RELU, bool BIAS, bool OUT_BF16, bool PARTIAL>
__global__ __launch_bounds__(256) void mfma_gemm_k(
    const unsigned short* __restrict__ xin, const unsigned short* __restrict__ Wr,
    const float* __restrict__ bias, void* __restrict__ out,
    int b_stride, int row_off, int row_t_stride,
    int To, int M, int t_off_out, int ldout, int Ktot, int Kloc)
{
  __shared__ __align__(16) short As[2][128 * 32];
  __shared__ __align__(16) short Bs[2][128 * 32];

  const int tid  = threadIdx.x;
  const int lane = tid & 63;
  const int wv   = tid >> 6;
  const int wr   = wv >> 1;        // wave row (2 waves over M)
  const int wc   = wv & 1;         // wave col (2 waves over N)
  const int mbase = blockIdx.x * 128;
  const int nbase = blockIdx.y * 128;
  const int kstart = PARTIAL ? blockIdx.z * Kloc : 0;

  // ---- staging: chunk c (0..511) = row (c>>2), 16B sub (c&3); thread owns
  // chunks tid (rows 0..63) and tid+256 (rows 64..127); swizzled sub.
  const int srow = tid >> 2;                       // 0..63
  const int sb   = (((tid & 3) ^ ((srow ^ (srow >> 2)) & 3))) * 8;
  int ma0 = min(mbase + srow,      M - 1);
  int ma1 = min(mbase + 64 + srow, M - 1);
  int ba0 = ma0 / To, ta0 = ma0 % To;
  int ba1 = ma1 / To, ta1 = ma1 % To;
  const unsigned short* agp0 = xin + (size_t)ba0 * b_stride + row_off
                               + (size_t)ta0 * row_t_stride + sb + kstart;
  const unsigned short* agp1 = xin + (size_t)ba1 * b_stride + row_off
                               + (size_t)ta1 * row_t_stride + sb + kstart;
  const unsigned short* bgp0 = Wr + (size_t)(nbase + srow) * Ktot + sb + kstart;
  const unsigned short* bgp1 = Wr + (size_t)(nbase + 64 + srow) * Ktot + sb + kstart;

  f32x4 acc[4][4] = {};
  const int nsteps = Kloc >> 5;

#define STAGE(buf, k0)                                        \
  do {                                                        \
    GLOAD_LDS16(agp0 + (k0), &As[buf][wv * 512]);             \
    GLOAD_LDS16(agp1 + (k0), &As[buf][2048 + wv * 512]);      \
    GLOAD_LDS16(bgp0 + (k0), &Bs[buf][wv * 512]);             \
    GLOAD_LDS16(bgp1 + (k0), &Bs[buf][2048 + wv * 512]);      \
  } while (0)

  STAGE(0, 0);
  __syncthreads();

  // ---- read offsets (same swizzle involution; fm*16 doesn't affect &3 term)
  const int l15   = lane & 15;
  const int rsw   = (l15 ^ (l15 >> 2)) & 3;
  const int chunk = ((lane >> 4) ^ rsw) * 8;
  const int a_off = (wr * 64 + l15) * 32 + chunk;
  const int b_off = (wc * 64 + l15) * 32 + chunk;

  for (int s = 0; s < nsteps; ++s) {
    const int nb = s & 1;
    if (s + 1 < nsteps) STAGE(nb ^ 1, (s + 1) * 32);

    const short* Ab = &As[nb][a_off];
    const short* Bb = &Bs[nb][b_off];
    short8 af[4], bf[4];
#pragma unroll
    for (int f = 0; f < 4; ++f) {
      af[f] = *reinterpret_cast<const short8*>(Ab + f * 512);   // +16 rows
      bf[f] = *reinterpret_cast<const short8*>(Bb + f * 512);
    }
#pragma unroll
    for (int fm = 0; fm < 4; ++fm)
#pragma unroll
      for (int fn = 0; fn < 4; ++fn)
        acc[fm][fn] = __builtin_amdgcn_mfma_f32_16x16x32_bf16(af[fm], bf[fn], acc[fm][fn], 0, 0, 0);

    __syncthreads();
  }
#undef STAGE

  // ---- epilogue: C/D map col=lane&15, row=4*(lane>>4)+reg ----
  const int cl = lane & 15, rh = lane >> 4;
#pragma unroll
  for (int fm = 0; fm < 4; ++fm) {
#pragma unroll
    for (int fn = 0; fn < 4; ++fn) {
      int col = nbase + wc * 64 + fn * 16 + cl;
      float bv = BIAS ? bias[col] : 0.f;
      f32x4 v = acc[fm][fn];
#pragma unroll
      for (int r = 0; r < 4; ++r) {
        int m = mbase + wr * 64 + fm * 16 + rh * 4 + r;
        if (m < M) {
          if (PARTIAL) {
            float* pout = (float*)out + (size_t)blockIdx.z * ((size_t)M * ldout);
            pout[(size_t)m * ldout + col] = v[r];
          } else {
            int b = m / To, to = m % To;
            float x = v[r] + bv;
            if (RELU) x = fmaxf(x, 0.f);
            size_t oi = ((size_t)b * TP_ + t_off_out + to) * (size_t)ldout + col;
            if (OUT_BF16) ((unsigned short*)out)[oi] = f2bf(x);
            else          ((float*)out)[oi] = x;
          }
        }
      }
    }
  }
}

// ---------------------------------------------------------------------------
// K-split reduce: sum S partials [S][M][512], +bias, relu, bf16, scatter to
// vcat rows.  thread = one float4 of one row.
// ---------------------------------------------------------------------------
template<int S>
__global__ void reduce_conv_k(const float* __restrict__ part, const float* __restrict__ bias,
                              unsigned short* __restrict__ outb,
                              int M, int To, int t_off_out) {
  int idx = blockIdx.x * 256 + threadIdx.x;      // over M*128 float4s
  int m = idx >> 7, n4 = idx & 127;
  if (m >= M) return;
  size_t off = (size_t)m * 512 + n4 * 4;
  float4 a = *reinterpret_cast<const float4*>(part + off);
#pragma unroll
  for (int s = 1; s < S; ++s) {
    float4 b = *reinterpret_cast<const float4*>(part + (size_t)s * M * 512 + off);
    a.x += b.x; a.y += b.y; a.z += b.z; a.w += b.w;
  }
  float4 bv = *reinterpret_cast<const float4*>(bias + n4 * 4);
  a.x = fmaxf(a.x + bv.x, 0.f);
  a.y = fmaxf(a.y + bv.y, 0.f);
  a.z = fmaxf(a.z + bv.z, 0.f);
  a.w = fmaxf(a.w + bv.w, 0.f);
  int b_ = m / To, to = m % To;
  ushort4_t h = { f2bf(a.x), f2bf(a.y), f2bf(a.z), f2bf(a.w) };
  reinterpret_cast<ushort4_t*>(outb + ((size_t)b_ * TP_ + t_off_out + to) * 512)[n4] = h;
}

// ---------------------------------------------------------------------------
// Normalize v2 in place (fp32), emit bf16 copy + row norms vn.
// ---------------------------------------------------------------------------
__global__ void v2_norm_vn_k(float* __restrict__ v2, const float* __restrict__ ms,
                             unsigned short* __restrict__ v2bf, float* __restrict__ vn) {
  int r = blockIdx.x, t = threadIdx.x;
  float* row = v2 + (size_t)r * DJ_;
  unsigned short* brow = v2bf + (size_t)r * DJ_;
  float ss = 0.f;
#pragma unroll
  for (int h = 0; h < 2; ++h) {
    int c4 = t + h * 64;
    float4 v = reinterpret_cast<float4*>(row)[c4];
    int c = c4 * 4;
    v.x = (v.x - ms[c+0]) * ms[DJ_+c+0];
    v.y = (v.y - ms[c+1]) * ms[DJ_+c+1];
    v.z = (v.z - ms[c+2]) * ms[DJ_+c+2];
    v.w = (v.w - ms[c+3]) * ms[DJ_+c+3];
    reinterpret_cast<float4*>(row)[c4] = v;
    ushort4_t h4 = { f2bf(v.x), f2bf(v.y), f2bf(v.z), f2bf(v.w) };
    reinterpret_cast<ushort4_t*>(brow)[c4] = h4;
    ss += v.x*v.x + v.y*v.y + v.z*v.z + v.w*v.w;
  }
#pragma unroll
  for (int o = 32; o; o >>= 1) ss += __shfl_down(ss, o, 64);
  if (t == 0) vn[r] = sqrtf(ss);
}

// words normalize -> fp32 (for gram) + bf16 (for attention GEMM)
__global__ void wnorm_k(const float* __restrict__ words, const float* __restrict__ ms,
                        float* __restrict__ wbn, unsigned short* __restrict__ wbnb) {
  int idx = blockIdx.x * 256 + threadIdx.x;
  if (idx >= (B_ * L_ * DJ_) / 4) return;
  int c = (idx & 127) * 4;
  float4 v = reinterpret_cast<const float4*>(words)[idx];
  v.x = (v.x - ms[c+0]) * ms[DJ_+c+0];
  v.y = (v.y - ms[c+1]) * ms[DJ_+c+1];
  v.z = (v.z - ms[c+2]) * ms[DJ_+c+2];
  v.w = (v.w - ms[c+3]) * ms[DJ_+c+3];
  reinterpret_cast<float4*>(wbn)[idx] = v;
  ushort4_t h = { f2bf(v.x), f2bf(v.y), f2bf(v.z), f2bf(v.w) };
  reinterpret_cast<ushort4_t*>(wbnb)[idx] = h;
}

// Per-sentence Gram matrices G[i][l][l'] = w_l . w_l'
__global__ void gram_k(const float* __restrict__ wbn, float* __restrict__ G) {
  __shared__ float sw[L_ * 516];
  int i = blockIdx.x, tid = threadIdx.x;
  for (int idx = tid; idx < L_ * DJ_; idx += 256) {
    int l = idx >> 9, d = idx & 511;
    sw[l * 516 + d] = wbn[(size_t)i * L_ * DJ_ + idx];
  }
  __syncthreads();
  for (int p = tid; p < L_ * L_; p += 256) {
    int l = p / L_, l2 = p % L_;
    const float4* a = reinterpret_cast<const float4*>(&sw[l * 516]);
    const float4* b = reinterpret_cast<const float4*>(&sw[l2 * 516]);
    float acc = 0.f;
    for (int d4 = 0; d4 < 128; ++d4) {
      float4 av = a[d4], bv = b[d4];
      acc += av.x*bv.x + av.y*bv.y + av.z*bv.z + av.w*bv.w;
    }
    G[i * 400 + p] = acc;
  }
}

// ---------------------------------------------------------------------------
// sim kernel
// ---------------------------------------------------------------------------
__global__ __launch_bounds__(256) void sim_k(
    const float* __restrict__ A, const float* __restrict__ G,
    const float* __restrict__ vn, const float* __restrict__ wmask,
    float* __restrict__ pos, float* __restrict__ scores) {
  int j = blockIdx.x, i = blockIdx.y;
  __shared__ float sG[400];
  __shared__ float sm[20];
  __shared__ float red[4];
  int tid = threadIdx.x;
  for (int p = tid; p < 400; p += 256) sG[p] = G[i * 400 + p];
  if (tid < 20) sm[tid] = wmask[i * 20 + tid];
  __syncthreads();

  float simv = -1e30f;
  if (tid < TP_) {
    const float* ar = A + ((size_t)j * TP_ + tid) * 640 + i * 20;
    float a[20], p[20];
    float mx = -1e30f;
#pragma unroll
    for (int l = 0; l < 20; ++l) {
      a[l] = ar[l];
      float lg = (sm[l] > 0.5f) ? LAM_ * a[l] : -1e9f;
      p[l] = lg;
      mx = fmaxf(mx, lg);
    }
    float Z = 0.f;
#pragma unroll
    for (int l = 0; l < 20; ++l) { p[l] = __expf(p[l] - mx); Z += p[l]; }
    float invZ = 1.f / Z, num = 0.f;
#pragma unroll
    for (int l = 0; l < 20; ++l) { p[l] *= invZ; num += p[l] * a[l]; }
    float q2 = 0.f;
#pragma unroll
    for (int l = 0; l < 20; ++l) {
      float gi = 0.f;
#pragma unroll
      for (int l2 = 0; l2 < 20; ++l2) gi += sG[l * 20 + l2] * p[l2];
      q2 += p[l] * gi;
    }
    float vnv = fmaxf(vn[(size_t)j * TP_ + tid], 1e-8f);
    float vsnv = fmaxf(sqrtf(q2), 1e-8f);
    simv = num / (vnv * vsnv);
    if (i == j) pos[i * TP_ + tid] = simv;
  }
  float mv = simv;
#pragma unroll
  for (int o = 32; o; o >>= 1) mv = fmaxf(mv, __shfl_down(mv, o, 64));
  if ((tid & 63) == 0) red[tid >> 6] = mv;
  __syncthreads();
  if (tid == 0)
    scores[i * 32 + j] = fmaxf(fmaxf(red[0], red[1]), fmaxf(red[2], red[3]));
}

// margin ranking loss over scores[32][32]
__global__ void loss_k(const float* __restrict__ scores, float* __restrict__ out) {
  __shared__ float red[16];
  int tid = threadIdx.x;
  int i = tid >> 5, j = tid & 31;
  float s = scores[tid];
  float dgi = scores[i * 32 + i], dgj = scores[j * 32 + j];
  float c = 0.f;
  if (i != j)
    c = fmaxf(0.f, MARGIN_ + s - dgi) + fmaxf(0.f, MARGIN_ + s - dgj);
#pragma unroll
  for (int o = 32; o; o >>= 1) c += __shfl_down(c, o, 64);
  if ((tid & 63) == 0) red[tid >> 6] = c;
  __syncthreads();
  if (tid == 0) {
    float t = 0.f;
    for (int w = 0; w < 16; ++w) t += red[w];
    out[0] = t / 32.f;
  }
}

// ---------------------------------------------------------------------------
extern "C" void kernel_launch(void* const* d_in, const int* in_sizes, int n_in,
                              void* d_out, int out_size, void* d_ws, size_t ws_size,
                              hipStream_t stream) {
  const float* video = (const float*)d_in[0];
  const float* words = (const float*)d_in[1];
  const float* wmask = (const float*)d_in[2];
  const float* c0w = (const float*)d_in[3];
  const float* c0b = (const float*)d_in[4];
  const float* c1w = (const float*)d_in[5];
  const float* c1b = (const float*)d_in[6];
  const float* c2w = (const float*)d_in[7];
  const float* c2b = (const float*)d_in[8];
  const float* pww = (const float*)d_in[9];
  const float* pwb = (const float*)d_in[10];
  float* out = (float*)d_out;
  float* ws  = (float*)d_ws;

  // workspace layout (float units).
  // Pbuf (K-split partial scratch, 8323072 f) OVERLAYS v2..: those arrays are
  // only written after the last conv reduce.  Amat overlays vbf.
  float*          W0r    = ws;                                  // 1048576
  float*          W1r    = W0r + 1048576;                       // 524288
  float*          W2r    = W1r + 524288;                        // 524288
  float*          Wpw    = W2r + 524288;                        // 131072
  float*          AMvbf  = Wpw + 131072;                        // 4485120  (vbf | Amat)
  float*          vcatb  = AMvbf + 4485120;                     // 1794048  (bf16 vcat)
  float*          Pbuf   = vcatb + 1794048;                     // 8323072  (overlay start)
  float*          v2     = Pbuf;                                // 3588096
  float*          v2bfp  = v2 + 3588096;                        // 1794048
  float*          wbn    = v2bfp + 1794048;                     // 327680
  float*          wbnbp  = wbn + 327680;                        // 163840
  float*          G      = wbnbp + 163840;                      // 12800
  float*          vn     = G + 12800;                           // 7008
  float*          scores = vn + 7008;                           // 1024
  float*          vpart  = scores + 1024;                       // 1048576
  float*          vms    = vpart + 1048576;                     // 2048
  float*          v2part = vms + 2048;                          // 897024
  float*          v2ms   = v2part + 897024;                     // 1024
  float*          wpart  = v2ms + 1024;                         // 81920
  float*          wms    = wpart + 81920;                       // 1024

  unsigned short* W0     = (unsigned short*)W0r;
  unsigned short* W1     = (unsigned short*)W1r;
  unsigned short* W2     = (unsigned short*)W2r;
  unsigned short* Wp     = (unsigned short*)Wpw;
  unsigned short* vbf    = (unsigned short*)AMvbf;
  float*          Amat   = AMvbf;
  unsigned short* vcb    = (unsigned short*)vcatb;
  unsigned short* v2bf   = (unsigned short*)v2bfp;
  unsigned short* wbnb   = (unsigned short*)wbnbp;

  // weight reorder + bf16 cast (single launch, coalesced)
  reorder_all_k<<<4352, 256, 0, stream>>>(c0w, c1w, c2w, pww, W0, W1, W2, Wp);

  // video BN stats + apply/cast   (8192 rows x 1024 ch)
  stats1_k<<<512, 256, 0, stream>>>(video, vpart, 1024, 8192, 16, 8);
  stats2_k<<<8, 256, 0, stream>>>(vpart, vms, 1024, 512, 1.f / 8192.f);
  vid_bn_cast_k<<<8192, 256, 0, stream>>>(video, vms, vbf);

  // ---- conv tower, K-split for occupancy, fp32 partials -> reduce ----
  // conv0: M=4064, K=4096 -> 4 x 1024   (512 blocks)
  mfma_gemm_k<false, false, false, true><<<dim3(32, 4, 4), 256, 0, stream>>>(
      vbf, W0, nullptr, Pbuf, 262144, 0, 2048, T0_, 32 * T0_, 0, 512, 4096, 1024);
  reduce_conv_k<4><<<2032, 256, 0, stream>>>(Pbuf, c0b, vcb, 32 * T0_, T0_, 0);
  // conv1: M=1984, K=2048 -> 8 x 256    (512 blocks)
  mfma_gemm_k<false, false, false, true><<<dim3(16, 4, 8), 256, 0, stream>>>(
      vcb, W1, nullptr, Pbuf, 112128, 0, 1024, T1_, 32 * T1_, 0, 512, 2048, 256);
  reduce_conv_k<8><<<992, 256, 0, stream>>>(Pbuf, c1b, vcb, 32 * T1_, T1_, T0_);
  // conv2: M=960, K=2048 -> 8 x 256     (256 blocks)
  mfma_gemm_k<false, false, false, true><<<dim3(8, 4, 8), 256, 0, stream>>>(
      vcb, W2, nullptr, Pbuf, 112128, 65024, 1024, T2_, 32 * T2_, 0, 512, 2048, 256);
  reduce_conv_k<8><<<480, 256, 0, stream>>>(Pbuf, c2b, vcb, 32 * T2_, T2_, T0_ + T1_);

  // pointwise conv -> v2 fp32 (220 blocks, unsplit)
  mfma_gemm_k<false, true, false, false><<<dim3(55, 4), 256, 0, stream>>>(
      vcb, Wp, pwb, v2, 112128, 0, 512, TP_, 32 * TP_, 0, 512, 512, 512);

  // v2 BN (+ bf16 copy + row norms)   (7008 rows x 512 ch)
  stats1_k<<<438, 256, 0, stream>>>(v2, v2part, 512, 7008, 16, 7);
  stats2_k<<<4, 256, 0, stream>>>(v2part, v2ms, 512, 876, 1.f / 7008.f);
  v2_norm_vn_k<<<7008, 64, 0, stream>>>(v2, v2ms, v2bf, vn);

  // words BN   (640 rows x 512 ch)
  stats1_k<<<40, 256, 0, stream>>>(words, wpart, 512, 640, 16, 7);
  stats2_k<<<4, 256, 0, stream>>>(wpart, wms, 512, 80, 1.f / 640.f);
  wnorm_k<<<(81920 + 255) / 256, 256, 0, stream>>>(words, wms, wbn, wbnb);
  gram_k<<<32, 256, 0, stream>>>(wbn, G);

  // A[(j,t)][(i,l)] = v . w  (M=7008, N=640, K=512) -> Amat fp32 (overlays vbf)
  mfma_gemm_k<false, false, false, false><<<dim3(55, 5), 256, 0, stream>>>(
      v2bf, wbnb, nullptr, Amat, 112128, 0, 512, TP_, 32 * TP_, 0, 640, 512, 512);

  // fused softmax / cosine-sim / scores / positive_map
  sim_k<<<dim3(32, 32), 256, 0, stream>>>(Amat, G, vn, wmask, out + 1, scores);
  loss_k<<<1, 1024, 0, stream>>>(scores, out);
}

// Round 7
// 244.296 us; speedup vs baseline: 1.0089x; 1.0089x over previous
//
#include <hip/hip_runtime.h>
#include <math.h>

// Problem constants
#define B_   32
#define T_   256
#define DV_  1024
#define DJ_  512
#define L_   20
#define T0_  127
#define T1_  62
#define T2_  30
#define TP_  219          // 127+62+30
#define LAM_ 4.0f
#define MARGIN_ 0.1f

typedef __attribute__((ext_vector_type(8))) short short8;
typedef __attribute__((ext_vector_type(4))) float f32x4;

static __device__ __forceinline__ unsigned short f2bf(float f) {
  union { float f; unsigned u; } v; v.f = f;
  unsigned r = v.u + 0x7fff + ((v.u >> 16) & 1);   // round-to-nearest-even
  return (unsigned short)(r >> 16);
}

struct ushort4_t { unsigned short x, y, z, w; };

#define GLOAD_LDS16(gp, lp)                                                      \
  __builtin_amdgcn_global_load_lds(                                              \
      (const __attribute__((address_space(1))) void*)(gp),                       \
      (__attribute__((address_space(3))) void*)(lp), 16, 0, 0)

// ---------------------------------------------------------------------------
// Weight reorder+cast, coalesced: thread = (co,ci), float4 read of 4 taps,
// 4 coalesced ushort stores at stride Cin.  pw = straight cast.
// ---------------------------------------------------------------------------
__global__ void reorder_all_k(const float* __restrict__ c0w, const float* __restrict__ c1w,
                              const float* __restrict__ c2w, const float* __restrict__ pww,
                              unsigned short* __restrict__ W0, unsigned short* __restrict__ W1,
                              unsigned short* __restrict__ W2, unsigned short* __restrict__ Wp) {
  int bid = blockIdx.x;
  if (bid < 2048) {            // conv0: 512*1024 (co,ci) pairs
    int idx = bid * 256 + threadIdx.x;
    int co = idx >> 10, ci = idx & 1023;
    float4 w = *reinterpret_cast<const float4*>(c0w + (size_t)idx * 4);
    unsigned short* d = W0 + (size_t)co * 4096 + ci;
    d[0] = f2bf(w.x); d[1024] = f2bf(w.y); d[2048] = f2bf(w.z); d[3072] = f2bf(w.w);
  } else if (bid < 3072) {     // conv1: 512*512
    int idx = (bid - 2048) * 256 + threadIdx.x;
    int co = idx >> 9, ci = idx & 511;
    float4 w = *reinterpret_cast<const float4*>(c1w + (size_t)idx * 4);
    unsigned short* d = W1 + (size_t)co * 2048 + ci;
    d[0] = f2bf(w.x); d[512] = f2bf(w.y); d[1024] = f2bf(w.z); d[1536] = f2bf(w.w);
  } else if (bid < 4096) {     // conv2: 512*512
    int idx = (bid - 3072) * 256 + threadIdx.x;
    int co = idx >> 9, ci = idx & 511;
    float4 w = *reinterpret_cast<const float4*>(c2w + (size_t)idx * 4);
    unsigned short* d = W2 + (size_t)co * 2048 + ci;
    d[0] = f2bf(w.x); d[512] = f2bf(w.y); d[1024] = f2bf(w.z); d[1536] = f2bf(w.w);
  } else {                     // pw: identity cast, 262144 elems / 4
    int idx = (bid - 4096) * 256 + threadIdx.x;
    float4 v = *reinterpret_cast<const float4*>(pww + (size_t)idx * 4);
    ushort4_t h = { f2bf(v.x), f2bf(v.y), f2bf(v.z), f2bf(v.w) };
    reinterpret_cast<ushort4_t*>(Wp)[idx] = h;
  }
}

// ---------------------------------------------------------------------------
// BatchNorm stats, two stage, deterministic, highly parallel.
// ---------------------------------------------------------------------------
__global__ void stats1_k(const float* __restrict__ x, float* __restrict__ part,
                         int C, int rows, int rpg, int cpgShift) {
  int cpg  = 1 << cpgShift;                 // C/4
  int c4   = threadIdx.x & (cpg - 1);
  int rsub = threadIdx.x >> cpgShift;
  int nsub = 256 >> cpgShift;
  int r0 = blockIdx.x * rpg + rsub;
  int r1 = min(blockIdx.x * rpg + rpg, rows);
  float4 s = {0.f,0.f,0.f,0.f}, q = {0.f,0.f,0.f,0.f};
  for (int r = r0; r < r1; r += nsub) {
    float4 v = *reinterpret_cast<const float4*>(&x[(size_t)r * C + c4 * 4]);
    s.x += v.x; s.y += v.y; s.z += v.z; s.w += v.w;
    q.x += v.x*v.x; q.y += v.y*v.y; q.z += v.z*v.z; q.w += v.w*v.w;
  }
  float* ps = part + ((size_t)blockIdx.x * nsub + rsub) * 2 * C;
  reinterpret_cast<float4*>(ps)[c4] = s;
  reinterpret_cast<float4*>(ps + C)[c4] = q;
}

// Stage 2: block handles 128 channels (32 float4); 8 g-stripes; LDS combine.
__global__ void stats2_k(const float* __restrict__ part, float* __restrict__ ms,
                         int C, int ng, float inv_n) {
  __shared__ float4 sS[8][33], sQ[8][33];
  int c4l = threadIdx.x & 31;
  int gs  = threadIdx.x >> 5;
  int c4  = blockIdx.x * 32 + c4l;          // float4 channel index
  float4 s = {0.f,0.f,0.f,0.f}, q = {0.f,0.f,0.f,0.f};
  for (int g = gs; g < ng; g += 8) {
    const float4* ps = reinterpret_cast<const float4*>(part + (size_t)g * 2 * C);
    float4 a = ps[c4];
    float4 b = ps[(C >> 2) + c4];
    s.x += a.x; s.y += a.y; s.z += a.z; s.w += a.w;
    q.x += b.x; q.y += b.y; q.z += b.z; q.w += b.w;
  }
  sS[gs][c4l] = s; sQ[gs][c4l] = q;
  __syncthreads();
  if (gs == 0) {
    float4 S = sS[0][c4l], Q = sQ[0][c4l];
#pragma unroll
    for (int k = 1; k < 8; ++k) {
      float4 a = sS[k][c4l], b = sQ[k][c4l];
      S.x += a.x; S.y += a.y; S.z += a.z; S.w += a.w;
      Q.x += b.x; Q.y += b.y; Q.z += b.z; Q.w += b.w;
    }
    int c = c4 * 4;
    float m0 = S.x * inv_n, m1 = S.y * inv_n, m2 = S.z * inv_n, m3 = S.w * inv_n;
    ms[c+0] = m0; ms[C+c+0] = rsqrtf(Q.x * inv_n - m0*m0 + 1e-5f);
    ms[c+1] = m1; ms[C+c+1] = rsqrtf(Q.y * inv_n - m1*m1 + 1e-5f);
    ms[c+2] = m2; ms[C+c+2] = rsqrtf(Q.z * inv_n - m2*m2 + 1e-5f);
    ms[c+3] = m3; ms[C+c+3] = rsqrtf(Q.w * inv_n - m3*m3 + 1e-5f);
  }
}

// video BN apply + cast to bf16
__global__ void vid_bn_cast_k(const float* __restrict__ video,
                              const float* __restrict__ ms,
                              unsigned short* __restrict__ vbf) {
  int i4 = blockIdx.x * 256 + threadIdx.x;
  float4 v = reinterpret_cast<const float4*>(video)[i4];
  int c = (i4 & 255) * 4;
  v.x = (v.x - ms[c+0]) * ms[1024+c+0];
  v.y = (v.y - ms[c+1]) * ms[1024+c+1];
  v.z = (v.z - ms[c+2]) * ms[1024+c+2];
  v.w = (v.w - ms[c+3]) * ms[1024+c+3];
  ushort4_t h = { f2bf(v.x), f2bf(v.y), f2bf(v.z), f2bf(v.w) };
  reinterpret_cast<ushort4_t*>(vbf)[i4] = h;
}

// ---------------------------------------------------------------------------
// MFMA bf16 GEMM, tile-size templated.  BK=32, 256 thr = 4 waves (2x2),
// wave tile (BM/2)x(BN/2), frags 16x16x32.  LDS linear, source-side chunk
// swizzle (same involution on read).  Bijective XCD swizzle on flattened
// block id (consecutive work ids share the B-panel -> same-XCD L2 reuse).
// PARTIAL: z-dim of the *work id* = K-split index, writes fp32 partial.
// ---------------------------------------------------------------------------
template<int BM, int BN, bool RELU, bool BIAS, bool OUT_BF16, bool PARTIAL>
__global__ __launch_bounds__(256) void gemm_k(
    const unsigned short* __restrict__ xin, const unsigned short* __restrict__ Wr,
    const float* __restrict__ bias, void* __restrict__ out,
    int b_stride, int row_off, int row_t_stride,
    int To, int M, int t_off_out, int ldout, int Ktot, int Kloc)
{
  constexpr int AI = BM / 64, BI = BN / 64;     // staging issues per side
  constexpr int FM = BM / 32, FN = BN / 32;     // frags per wave
  __shared__ __align__(16) short As[2][BM * 32];
  __shared__ __align__(16) short Bs[2][BN * 32];

  const int tid  = threadIdx.x;
  const int lane = tid & 63;
  const int wv   = tid >> 6;
  const int wr   = wv >> 1;
  const int wc   = wv & 1;

  // ---- bijective XCD swizzle of the flattened block id (m204) ----
  const int gx = gridDim.x, gy = gridDim.y;
  const int nwg = gx * gy * gridDim.z;
  const int lin = blockIdx.x + gx * (blockIdx.y + gy * blockIdx.z);
  const int q = nwg >> 3, r = nwg & 7;
  const int xcd = lin & 7, sub = lin >> 3;
  const int work = (xcd < r ? xcd * (q + 1) : r * (q + 1) + (xcd - r) * q) + sub;
  const int bx = work % gx;
  const int by = (work / gx) % gy;
  const int bz = work / (gx * gy);

  const int mbase = bx * BM;
  const int nbase = by * BN;
  const int kstart = PARTIAL ? bz * Kloc : 0;

  // ---- staging: chunk c = row (c>>2), 16B sub (c&3), swizzled source sub.
  const int srow = tid >> 2;                       // 0..63
  const int sb   = (((tid & 3) ^ ((srow ^ (srow >> 2)) & 3))) * 8;
  const unsigned short* agp[AI];
  const unsigned short* bgp[BI];
#pragma unroll
  for (int i = 0; i < AI; ++i) {
    int ma = min(mbase + i * 64 + srow, M - 1);
    int b0 = ma / To, t0 = ma % To;
    agp[i] = xin + (size_t)b0 * b_stride + row_off
             + (size_t)t0 * row_t_stride + sb + kstart;
  }
#pragma unroll
  for (int i = 0; i < BI; ++i)
    bgp[i] = Wr + (size_t)(nbase + i * 64 + srow) * Ktot + sb + kstart;

  f32x4 acc[FM][FN] = {};
  const int nsteps = Kloc >> 5;

#define STAGE(buf, k0)                                                \
  do {                                                                \
    _Pragma("unroll")                                                 \
    for (int i = 0; i < AI; ++i)                                      \
      GLOAD_LDS16(agp[i] + (k0), &As[buf][i * 2048 + wv * 512]);      \
    _Pragma("unroll")                                                 \
    for (int i = 0; i < BI; ++i)                                      \
      GLOAD_LDS16(bgp[i] + (k0), &Bs[buf][i * 2048 + wv * 512]);      \
  } while (0)

  STAGE(0, 0);
  __syncthreads();

  // ---- read offsets (same swizzle involution; fm*16 rows keep (&3) term) --
  const int l15   = lane & 15;
  const int rsw   = (l15 ^ (l15 >> 2)) & 3;
  const int chunk = ((lane >> 4) ^ rsw) * 8;
  const int a_off = (wr * (BM / 2) + l15) * 32 + chunk;
  const int b_off = (wc * (BN / 2) + l15) * 32 + chunk;

  for (int s = 0; s < nsteps; ++s) {
    const int nb = s & 1;
    if (s + 1 < nsteps) STAGE(nb ^ 1, (s + 1) * 32);

    const short* Ab = &As[nb][a_off];
    const short* Bb = &Bs[nb][b_off];
    short8 af[FM], bf[FN];
#pragma unroll
    for (int f = 0; f < FM; ++f)
      af[f] = *reinterpret_cast<const short8*>(Ab + f * 512);
#pragma unroll
    for (int f = 0; f < FN; ++f)
      bf[f] = *reinterpret_cast<const short8*>(Bb + f * 512);
#pragma unroll
    for (int fm = 0; fm < FM; ++fm)
#pragma unroll
      for (int fn = 0; fn < FN; ++fn)
        acc[fm][fn] = __builtin_amdgcn_mfma_f32_16x16x32_bf16(af[fm], bf[fn], acc[fm][fn], 0, 0, 0);

    __syncthreads();
  }
#undef STAGE

  // ---- epilogue: C/D map col=lane&15, row=4*(lane>>4)+reg ----
  const int cl = lane & 15, rh = lane >> 4;
#pragma unroll
  for (int fm = 0; fm < FM; ++fm) {
#pragma unroll
    for (int fn = 0; fn < FN; ++fn) {
      int col = nbase + wc * (BN / 2) + fn * 16 + cl;
      float bv = BIAS ? bias[col] : 0.f;
      f32x4 v = acc[fm][fn];
#pragma unroll
      for (int rr = 0; rr < 4; ++rr) {
        int m = mbase + wr * (BM / 2) + fm * 16 + rh * 4 + rr;
        if (m < M) {
          if (PARTIAL) {
            float* pout = (float*)out + (size_t)bz * ((size_t)M * ldout);
            pout[(size_t)m * ldout + col] = v[rr];
          } else {
            int b = m / To, to = m % To;
            float x = v[rr] + bv;
            if (RELU) x = fmaxf(x, 0.f);
            size_t oi = ((size_t)b * TP_ + t_off_out + to) * (size_t)ldout + col;
            if (OUT_BF16) ((unsigned short*)out)[oi] = f2bf(x);
            else          ((float*)out)[oi] = x;
          }
        }
      }
    }
  }
}

// ---------------------------------------------------------------------------
// K-split reduce: sum S partials [S][M][512], +bias, relu, bf16, scatter to
// vcat rows.  thread = one float4 of one row.
// ---------------------------------------------------------------------------
template<int S>
__global__ void reduce_conv_k(const float* __restrict__ part, const float* __restrict__ bias,
                              unsigned short* __restrict__ outb,
                              int M, int To, int t_off_out) {
  int idx = blockIdx.x * 256 + threadIdx.x;      // over M*128 float4s
  int m = idx >> 7, n4 = idx & 127;
  if (m >= M) return;
  size_t off = (size_t)m * 512 + n4 * 4;
  float4 a = *reinterpret_cast<const float4*>(part + off);
#pragma unroll
  for (int s = 1; s < S; ++s) {
    float4 b = *reinterpret_cast<const float4*>(part + (size_t)s * M * 512 + off);
    a.x += b.x; a.y += b.y; a.z += b.z; a.w += b.w;
  }
  float4 bv = *reinterpret_cast<const float4*>(bias + n4 * 4);
  a.x = fmaxf(a.x + bv.x, 0.f);
  a.y = fmaxf(a.y + bv.y, 0.f);
  a.z = fmaxf(a.z + bv.z, 0.f);
  a.w = fmaxf(a.w + bv.w, 0.f);
  int b_ = m / To, to = m % To;
  ushort4_t h = { f2bf(a.x), f2bf(a.y), f2bf(a.z), f2bf(a.w) };
  reinterpret_cast<ushort4_t*>(outb + ((size_t)b_ * TP_ + t_off_out + to) * 512)[n4] = h;
}

// ---------------------------------------------------------------------------
// Normalize v2 in place (fp32), emit bf16 copy + row norms vn.
// ---------------------------------------------------------------------------
__global__ void v2_norm_vn_k(float* __restrict__ v2, const float* __restrict__ ms,
                             unsigned short* __restrict__ v2bf, float* __restrict__ vn) {
  int r = blockIdx.x, t = threadIdx.x;
  float* row = v2 + (size_t)r * DJ_;
  unsigned short* brow = v2bf + (size_t)r * DJ_;
  float ss = 0.f;
#pragma unroll
  for (int h = 0; h < 2; ++h) {
    int c4 = t + h * 64;
    float4 v = reinterpret_cast<float4*>(row)[c4];
    int c = c4 * 4;
    v.x = (v.x - ms[c+0]) * ms[DJ_+c+0];
    v.y = (v.y - ms[c+1]) * ms[DJ_+c+1];
    v.z = (v.z - ms[c+2]) * ms[DJ_+c+2];
    v.w = (v.w - ms[c+3]) * ms[DJ_+c+3];
    reinterpret_cast<float4*>(row)[c4] = v;
    ushort4_t h4 = { f2bf(v.x), f2bf(v.y), f2bf(v.z), f2bf(v.w) };
    reinterpret_cast<ushort4_t*>(brow)[c4] = h4;
    ss += v.x*v.x + v.y*v.y + v.z*v.z + v.w*v.w;
  }
#pragma unroll
  for (int o = 32; o; o >>= 1) ss += __shfl_down(ss, o, 64);
  if (t == 0) vn[r] = sqrtf(ss);
}

// words normalize -> fp32 (for gram) + bf16 (for attention GEMM)
__global__ void wnorm_k(const float* __restrict__ words, const float* __restrict__ ms,
                        float* __restrict__ wbn, unsigned short* __restrict__ wbnb) {
  int idx = blockIdx.x * 256 + threadIdx.x;
  if (idx >= (B_ * L_ * DJ_) / 4) return;
  int c = (idx & 127) * 4;
  float4 v = reinterpret_cast<const float4*>(words)[idx];
  v.x = (v.x - ms[c+0]) * ms[DJ_+c+0];
  v.y = (v.y - ms[c+1]) * ms[DJ_+c+1];
  v.z = (v.z - ms[c+2]) * ms[DJ_+c+2];
  v.w = (v.w - ms[c+3]) * ms[DJ_+c+3];
  reinterpret_cast<float4*>(wbn)[idx] = v;
  ushort4_t h = { f2bf(v.x), f2bf(v.y), f2bf(v.z), f2bf(v.w) };
  reinterpret_cast<ushort4_t*>(wbnb)[idx] = h;
}

// Per-sentence Gram matrices G[i][l][l'] = w_l . w_l'
__global__ void gram_k(const float* __restrict__ wbn, float* __restrict__ G) {
  __shared__ float sw[L_ * 516];
  int i = blockIdx.x, tid = threadIdx.x;
  for (int idx = tid; idx < L_ * DJ_; idx += 256) {
    int l = idx >> 9, d = idx & 511;
    sw[l * 516 + d] = wbn[(size_t)i * L_ * DJ_ + idx];
  }
  __syncthreads();
  for (int p = tid; p < L_ * L_; p += 256) {
    int l = p / L_, l2 = p % L_;
    const float4* a = reinterpret_cast<const float4*>(&sw[l * 516]);
    const float4* b = reinterpret_cast<const float4*>(&sw[l2 * 516]);
    float acc = 0.f;
    for (int d4 = 0; d4 < 128; ++d4) {
      float4 av = a[d4], bv = b[d4];
      acc += av.x*bv.x + av.y*bv.y + av.z*bv.z + av.w*bv.w;
    }
    G[i * 400 + p] = acc;
  }
}

// ---------------------------------------------------------------------------
// sim kernel
// ---------------------------------------------------------------------------
__global__ __launch_bounds__(256) void sim_k(
    const float* __restrict__ A, const float* __restrict__ G,
    const float* __restrict__ vn, const float* __restrict__ wmask,
    float* __restrict__ pos, float* __restrict__ scores) {
  int j = blockIdx.x, i = blockIdx.y;
  __shared__ float sG[400];
  __shared__ float sm[20];
  __shared__ float red[4];
  int tid = threadIdx.x;
  for (int p = tid; p < 400; p += 256) sG[p] = G[i * 400 + p];
  if (tid < 20) sm[tid] = wmask[i * 20 + tid];
  __syncthreads();

  float simv = -1e30f;
  if (tid < TP_) {
    const float* ar = A + ((size_t)j * TP_ + tid) * 640 + i * 20;
    float a[20], p[20];
    float mx = -1e30f;
#pragma unroll
    for (int l = 0; l < 20; ++l) {
      a[l] = ar[l];
      float lg = (sm[l] > 0.5f) ? LAM_ * a[l] : -1e9f;
      p[l] = lg;
      mx = fmaxf(mx, lg);
    }
    float Z = 0.f;
#pragma unroll
    for (int l = 0; l < 20; ++l) { p[l] = __expf(p[l] - mx); Z += p[l]; }
    float invZ = 1.f / Z, num = 0.f;
#pragma unroll
    for (int l = 0; l < 20; ++l) { p[l] *= invZ; num += p[l] * a[l]; }
    float q2 = 0.f;
#pragma unroll
    for (int l = 0; l < 20; ++l) {
      float gi = 0.f;
#pragma unroll
      for (int l2 = 0; l2 < 20; ++l2) gi += sG[l * 20 + l2] * p[l2];
      q2 += p[l] * gi;
    }
    float vnv = fmaxf(vn[(size_t)j * TP_ + tid], 1e-8f);
    float vsnv = fmaxf(sqrtf(q2), 1e-8f);
    simv = num / (vnv * vsnv);
    if (i == j) pos[i * TP_ + tid] = simv;
  }
  float mv = simv;
#pragma unroll
  for (int o = 32; o; o >>= 1) mv = fmaxf(mv, __shfl_down(mv, o, 64));
  if ((tid & 63) == 0) red[tid >> 6] = mv;
  __syncthreads();
  if (tid == 0)
    scores[i * 32 + j] = fmaxf(fmaxf(red[0], red[1]), fmaxf(red[2], red[3]));
}

// margin ranking loss over scores[32][32]
__global__ void loss_k(const float* __restrict__ scores, float* __restrict__ out) {
  __shared__ float red[16];
  int tid = threadIdx.x;
  int i = tid >> 5, j = tid & 31;
  float s = scores[tid];
  float dgi = scores[i * 32 + i], dgj = scores[j * 32 + j];
  float c = 0.f;
  if (i != j)
    c = fmaxf(0.f, MARGIN_ + s - dgi) + fmaxf(0.f, MARGIN_ + s - dgj);
#pragma unroll
  for (int o = 32; o; o >>= 1) c += __shfl_down(c, o, 64);
  if ((tid & 63) == 0) red[tid >> 6] = c;
  __syncthreads();
  if (tid == 0) {
    float t = 0.f;
    for (int w = 0; w < 16; ++w) t += red[w];
    out[0] = t / 32.f;
  }
}

// ---------------------------------------------------------------------------
extern "C" void kernel_launch(void* const* d_in, const int* in_sizes, int n_in,
                              void* d_out, int out_size, void* d_ws, size_t ws_size,
                              hipStream_t stream) {
  const float* video = (const float*)d_in[0];
  const float* words = (const float*)d_in[1];
  const float* wmask = (const float*)d_in[2];
  const float* c0w = (const float*)d_in[3];
  const float* c0b = (const float*)d_in[4];
  const float* c1w = (const float*)d_in[5];
  const float* c1b = (const float*)d_in[6];
  const float* c2w = (const float*)d_in[7];
  const float* c2b = (const float*)d_in[8];
  const float* pww = (const float*)d_in[9];
  const float* pwb = (const float*)d_in[10];
  float* out = (float*)d_out;
  float* ws  = (float*)d_ws;

  // workspace layout (float units).
  // Pbuf (K-split partial scratch, 8323072 f) OVERLAYS v2..: those arrays are
  // only written after the last conv reduce.  Amat overlays vbf.
  float*          W0r    = ws;                                  // 1048576
  float*          W1r    = W0r + 1048576;                       // 524288
  float*          W2r    = W1r + 524288;                        // 524288
  float*          Wpw    = W2r + 524288;                        // 131072
  float*          AMvbf  = Wpw + 131072;                        // 4485120  (vbf | Amat)
  float*          vcatb  = AMvbf + 4485120;                     // 1794048  (bf16 vcat)
  float*          Pbuf   = vcatb + 1794048;                     // 8323072  (overlay start)
  float*          v2     = Pbuf;                                // 3588096
  float*          v2bfp  = v2 + 3588096;                        // 1794048
  float*          wbn    = v2bfp + 1794048;                     // 327680
  float*          wbnbp  = wbn + 327680;                        // 163840
  float*          G      = wbnbp + 163840;                      // 12800
  float*          vn     = G + 12800;                           // 7008
  float*          scores = vn + 7008;                           // 1024
  float*          vpart  = scores + 1024;                       // 1048576
  float*          vms    = vpart + 1048576;                     // 2048
  float*          v2part = vms + 2048;                          // 897024
  float*          v2ms   = v2part + 897024;                     // 1024
  float*          wpart  = v2ms + 1024;                         // 81920
  float*          wms    = wpart + 81920;                       // 1024

  unsigned short* W0     = (unsigned short*)W0r;
  unsigned short* W1     = (unsigned short*)W1r;
  unsigned short* W2     = (unsigned short*)W2r;
  unsigned short* Wp     = (unsigned short*)Wpw;
  unsigned short* vbf    = (unsigned short*)AMvbf;
  float*          Amat   = AMvbf;
  unsigned short* vcb    = (unsigned short*)vcatb;
  unsigned short* v2bf   = (unsigned short*)v2bfp;
  unsigned short* wbnb   = (unsigned short*)wbnbp;

  // weight reorder + bf16 cast (single launch, coalesced)
  reorder_all_k<<<4352, 256, 0, stream>>>(c0w, c1w, c2w, pww, W0, W1, W2, Wp);

  // video BN stats + apply/cast   (8192 rows x 1024 ch)
  stats1_k<<<512, 256, 0, stream>>>(video, vpart, 1024, 8192, 16, 8);
  stats2_k<<<8, 256, 0, stream>>>(vpart, vms, 1024, 512, 1.f / 8192.f);
  vid_bn_cast_k<<<8192, 256, 0, stream>>>(video, vms, vbf);

  // ---- conv tower, K-split for occupancy, fp32 partials -> reduce ----
  // conv0: M=4064, K=4096 -> 4x1024.  64x128 tile, (64,4,4)=1024 blk (4/CU)
  gemm_k<64, 128, false, false, false, true><<<dim3(64, 4, 4), 256, 0, stream>>>(
      vbf, W0, nullptr, Pbuf, 262144, 0, 2048, T0_, 32 * T0_, 0, 512, 4096, 1024);
  reduce_conv_k<4><<<2032, 256, 0, stream>>>(Pbuf, c0b, vcb, 32 * T0_, T0_, 0);
  // conv1: M=1984, K=2048 -> 8x256.  64x128 tile, (31,4,8)=992 blk
  gemm_k<64, 128, false, false, false, true><<<dim3(31, 4, 8), 256, 0, stream>>>(
      vcb, W1, nullptr, Pbuf, 112128, 0, 1024, T1_, 32 * T1_, 0, 512, 2048, 256);
  reduce_conv_k<8><<<992, 256, 0, stream>>>(Pbuf, c1b, vcb, 32 * T1_, T1_, T0_);
  // conv2: M=960, K=2048 -> 8x256.  64x64 tile, (15,8,8)=960 blk
  gemm_k<64, 64, false, false, false, true><<<dim3(15, 8, 8), 256, 0, stream>>>(
      vcb, W2, nullptr, Pbuf, 112128, 65024, 1024, T2_, 32 * T2_, 0, 512, 2048, 256);
  reduce_conv_k<8><<<480, 256, 0, stream>>>(Pbuf, c2b, vcb, 32 * T2_, T2_, T0_ + T1_);

  // pointwise conv -> v2 fp32.  64x64 tile, (110,8)=880 blk
  gemm_k<64, 64, false, true, false, false><<<dim3(110, 8), 256, 0, stream>>>(
      vcb, Wp, pwb, v2, 112128, 0, 512, TP_, 32 * TP_, 0, 512, 512, 512);

  // v2 BN (+ bf16 copy + row norms)   (7008 rows x 512 ch)
  stats1_k<<<438, 256, 0, stream>>>(v2, v2part, 512, 7008, 16, 7);
  stats2_k<<<4, 256, 0, stream>>>(v2part, v2ms, 512, 876, 1.f / 7008.f);
  v2_norm_vn_k<<<7008, 64, 0, stream>>>(v2, v2ms, v2bf, vn);

  // words BN   (640 rows x 512 ch)
  stats1_k<<<40, 256, 0, stream>>>(words, wpart, 512, 640, 16, 7);
  stats2_k<<<4, 256, 0, stream>>>(wpart, wms, 512, 80, 1.f / 640.f);
  wnorm_k<<<(81920 + 255) / 256, 256, 0, stream>>>(words, wms, wbn, wbnb);
  gram_k<<<32, 256, 0, stream>>>(wbn, G);

  // A[(j,t)][(i,l)] = v . w  (M=7008, N=640, K=512).  64x64 tile, (110,10)
  gemm_k<64, 64, false, false, false, false><<<dim3(110, 10), 256, 0, stream>>>(
      v2bf, wbnb, nullptr, Amat, 112128, 0, 512, TP_, 32 * TP_, 0, 640, 512, 512);

  // fused softmax / cosine-sim / scores / positive_map
  sim_k<<<dim3(32, 32), 256, 0, stream>>>(Amat, G, vn, wmask, out + 1, scores);
  loss_k<<<1, 1024, 0, stream>>>(scores, out);
}

// Round 9
// 206.041 us; speedup vs baseline: 1.1962x; 1.1857x over previous
//
#include <hip/hip_runtime.h>
#include <math.h>

// Problem constants
#define B_   32
#define T_   256
#define DV_  1024
#define DJ_  512
#define L_   20
#define T0_  127
#define T1_  62
#define T2_  30
#define TP_  219          // 127+62+30
#define LAM_ 4.0f
#define MARGIN_ 0.1f

typedef __attribute__((ext_vector_type(8))) short short8;
typedef __attribute__((ext_vector_type(4))) float f32x4;

static __device__ __forceinline__ unsigned short f2bf(float f) {
  union { float f; unsigned u; } v; v.f = f;
  unsigned r = v.u + 0x7fff + ((v.u >> 16) & 1);   // round-to-nearest-even
  return (unsigned short)(r >> 16);
}

struct ushort4_t { unsigned short x, y, z, w; };

#define GLOAD_LDS16(gp, lp)                                                      \
  __builtin_amdgcn_global_load_lds(                                              \
      (const __attribute__((address_space(1))) void*)(gp),                       \
      (__attribute__((address_space(3))) void*)(lp), 16, 0, 0)

// ---------------------------------------------------------------------------
// BatchNorm stats bodies (deterministic two-stage), shared by fused kernels.
// ---------------------------------------------------------------------------
__device__ __forceinline__ void stats1_body(const float* __restrict__ x,
                                            float* __restrict__ part,
                                            int C, int rows, int rpg, int cpgShift,
                                            int bid, int tid) {
  int cpg  = 1 << cpgShift;                 // C/4
  int c4   = tid & (cpg - 1);
  int rsub = tid >> cpgShift;
  int nsub = 256 >> cpgShift;
  int r0 = bid * rpg + rsub;
  int r1 = min(bid * rpg + rpg, rows);
  float4 s = {0.f,0.f,0.f,0.f}, q = {0.f,0.f,0.f,0.f};
  for (int r = r0; r < r1; r += nsub) {
    float4 v = *reinterpret_cast<const float4*>(&x[(size_t)r * C + c4 * 4]);
    s.x += v.x; s.y += v.y; s.z += v.z; s.w += v.w;
    q.x += v.x*v.x; q.y += v.y*v.y; q.z += v.z*v.z; q.w += v.w*v.w;
  }
  float* ps = part + ((size_t)bid * nsub + rsub) * 2 * C;
  reinterpret_cast<float4*>(ps)[c4] = s;
  reinterpret_cast<float4*>(ps + C)[c4] = q;
}

__device__ __forceinline__ void stats2_body(const float* __restrict__ part,
                                            float* __restrict__ ms,
                                            int C, int ng, float inv_n,
                                            int bid, int tid,
                                            float4* sS, float4* sQ) {
  int c4l = tid & 31;
  int gs  = tid >> 5;
  int c4  = bid * 32 + c4l;                 // float4 channel index
  float4 s = {0.f,0.f,0.f,0.f}, q = {0.f,0.f,0.f,0.f};
  for (int g = gs; g < ng; g += 8) {
    const float4* ps = reinterpret_cast<const float4*>(part + (size_t)g * 2 * C);
    float4 a = ps[c4];
    float4 b = ps[(C >> 2) + c4];
    s.x += a.x; s.y += a.y; s.z += a.z; s.w += a.w;
    q.x += b.x; q.y += b.y; q.z += b.z; q.w += b.w;
  }
  sS[gs * 33 + c4l] = s; sQ[gs * 33 + c4l] = q;
  __syncthreads();
  if (gs == 0) {
    float4 S = sS[c4l], Q = sQ[c4l];
#pragma unroll
    for (int k = 1; k < 8; ++k) {
      float4 a = sS[k * 33 + c4l], b = sQ[k * 33 + c4l];
      S.x += a.x; S.y += a.y; S.z += a.z; S.w += a.w;
      Q.x += b.x; Q.y += b.y; Q.z += b.z; Q.w += b.w;
    }
    int c = c4 * 4;
    float m0 = S.x * inv_n, m1 = S.y * inv_n, m2 = S.z * inv_n, m3 = S.w * inv_n;
    ms[c+0] = m0; ms[C+c+0] = rsqrtf(Q.x * inv_n - m0*m0 + 1e-5f);
    ms[c+1] = m1; ms[C+c+1] = rsqrtf(Q.y * inv_n - m1*m1 + 1e-5f);
    ms[c+2] = m2; ms[C+c+2] = rsqrtf(Q.z * inv_n - m2*m2 + 1e-5f);
    ms[c+3] = m3; ms[C+c+3] = rsqrtf(Q.w * inv_n - m3*m3 + 1e-5f);
  }
}

// ---------------------------------------------------------------------------
// prep_k: weight reorder+cast (4352 blocks) | video stats1 (512) | words
// stats1 (40).  All independent -> one launch.
// ---------------------------------------------------------------------------
__global__ void prep_k(const float* __restrict__ c0w, const float* __restrict__ c1w,
                       const float* __restrict__ c2w, const float* __restrict__ pww,
                       unsigned short* __restrict__ W0, unsigned short* __restrict__ W1,
                       unsigned short* __restrict__ W2, unsigned short* __restrict__ Wp,
                       const float* __restrict__ video, float* __restrict__ vpart,
                       const float* __restrict__ words, float* __restrict__ wpart) {
  int bid = blockIdx.x, tid = threadIdx.x;
  if (bid < 2048) {            // conv0: 512*1024 (co,ci) pairs
    int idx = bid * 256 + tid;
    int co = idx >> 10, ci = idx & 1023;
    float4 w = *reinterpret_cast<const float4*>(c0w + (size_t)idx * 4);
    unsigned short* d = W0 + (size_t)co * 4096 + ci;
    d[0] = f2bf(w.x); d[1024] = f2bf(w.y); d[2048] = f2bf(w.z); d[3072] = f2bf(w.w);
  } else if (bid < 3072) {     // conv1
    int idx = (bid - 2048) * 256 + tid;
    int co = idx >> 9, ci = idx & 511;
    float4 w = *reinterpret_cast<const float4*>(c1w + (size_t)idx * 4);
    unsigned short* d = W1 + (size_t)co * 2048 + ci;
    d[0] = f2bf(w.x); d[512] = f2bf(w.y); d[1024] = f2bf(w.z); d[1536] = f2bf(w.w);
  } else if (bid < 4096) {     // conv2
    int idx = (bid - 3072) * 256 + tid;
    int co = idx >> 9, ci = idx & 511;
    float4 w = *reinterpret_cast<const float4*>(c2w + (size_t)idx * 4);
    unsigned short* d = W2 + (size_t)co * 2048 + ci;
    d[0] = f2bf(w.x); d[512] = f2bf(w.y); d[1024] = f2bf(w.z); d[1536] = f2bf(w.w);
  } else if (bid < 4352) {     // pw identity cast
    int idx = (bid - 4096) * 256 + tid;
    float4 v = *reinterpret_cast<const float4*>(pww + (size_t)idx * 4);
    ushort4_t h = { f2bf(v.x), f2bf(v.y), f2bf(v.z), f2bf(v.w) };
    reinterpret_cast<ushort4_t*>(Wp)[idx] = h;
  } else if (bid < 4864) {     // video stats1 (8192 rows x 1024 ch)
    stats1_body(video, vpart, 1024, 8192, 16, 8, bid - 4352, tid);
  } else {                     // words stats1 (640 rows x 512 ch)
    stats1_body(words, wpart, 512, 640, 16, 7, bid - 4864, tid);
  }
}

// stats2 combo: video (8 blocks) + words (4 blocks)
__global__ void stats2c_k(const float* __restrict__ vpart, float* __restrict__ vms,
                          const float* __restrict__ wpart, float* __restrict__ wms) {
  __shared__ float4 sS[8 * 33], sQ[8 * 33];
  int bid = blockIdx.x, tid = threadIdx.x;
  if (bid < 8) stats2_body(vpart, vms, 1024, 512, 1.f / 8192.f, bid, tid, sS, sQ);
  else         stats2_body(wpart, wms, 512,  80,  1.f / 640.f,  bid - 8, tid, sS, sQ);
}

// standalone stats2 (v2 path)
__global__ void stats2_k(const float* __restrict__ part, float* __restrict__ ms,
                         int C, int ng, float inv_n) {
  __shared__ float4 sS[8 * 33], sQ[8 * 33];
  stats2_body(part, ms, C, ng, inv_n, blockIdx.x, threadIdx.x, sS, sQ);
}

// ---------------------------------------------------------------------------
// cast_wgram_k: video BN apply+cast (8192 blocks) | words BN->bf16 + Gram (32)
// ---------------------------------------------------------------------------
__global__ void cast_wgram_k(const float* __restrict__ video, const float* __restrict__ vms,
                             unsigned short* __restrict__ vbf,
                             const float* __restrict__ words, const float* __restrict__ wms,
                             unsigned short* __restrict__ wbnb, float* __restrict__ G) {
  __shared__ float sw[L_ * 516];
  int bid = blockIdx.x, tid = threadIdx.x;
  if (bid < 8192) {
    int i4 = bid * 256 + tid;
    float4 v = reinterpret_cast<const float4*>(video)[i4];
    int c = (i4 & 255) * 4;
    v.x = (v.x - vms[c+0]) * vms[1024+c+0];
    v.y = (v.y - vms[c+1]) * vms[1024+c+1];
    v.z = (v.z - vms[c+2]) * vms[1024+c+2];
    v.w = (v.w - vms[c+3]) * vms[1024+c+3];
    ushort4_t h = { f2bf(v.x), f2bf(v.y), f2bf(v.z), f2bf(v.w) };
    reinterpret_cast<ushort4_t*>(vbf)[i4] = h;
  } else {
    int i = bid - 8192;                      // sentence
    for (int idx = tid; idx < L_ * DJ_; idx += 256) {
      int l = idx >> 9, d = idx & 511;
      float x = (words[(size_t)i * L_ * DJ_ + idx] - wms[d]) * wms[DJ_ + d];
      sw[l * 516 + d] = x;
      wbnb[(size_t)i * L_ * DJ_ + idx] = f2bf(x);
    }
    __syncthreads();
    for (int p = tid; p < L_ * L_; p += 256) {
      int l = p / L_, l2 = p % L_;
      const float4* a = reinterpret_cast<const float4*>(&sw[l * 516]);
      const float4* b = reinterpret_cast<const float4*>(&sw[l2 * 516]);
      float acc = 0.f;
      for (int d4 = 0; d4 < 128; ++d4) {
        float4 av = a[d4], bv = b[d4];
        acc += av.x*bv.x + av.y*bv.y + av.z*bv.z + av.w*bv.w;
      }
      G[i * 400 + p] = acc;
    }
  }
}

// ---------------------------------------------------------------------------
// MFMA bf16 GEMM, tile-templated.  BK=32, 256 thr = 4 waves (2x2), wave tile
// (BM/2)x(BN/2).  LDS linear + source-side chunk swizzle (involution on read).
// Bijective XCD swizzle on flattened block id.  PARTIAL: K-split partials.
// STATS (64x64 only): deterministic per-block column sum/sumsq epilogue into
// spart[bx][2][512] for a fused BN-stats stage 1.
// ---------------------------------------------------------------------------
template<int BM, int BN, bool RELU, bool BIAS, bool OUT_BF16, bool PARTIAL, bool STATS>
__global__ __launch_bounds__(256) void gemm_k(
    const unsigned short* __restrict__ xin, const unsigned short* __restrict__ Wr,
    const float* __restrict__ bias, void* __restrict__ out, float* __restrict__ spart,
    int b_stride, int row_off, int row_t_stride,
    int To, int M, int t_off_out, int ldout, int Ktot, int Kloc)
{
  constexpr int AI = BM / 64, BI = BN / 64;     // staging issues per side
  constexpr int FM = BM / 32, FN = BN / 32;     // frags per wave
  __shared__ __align__(16) short As[2][BM * 32];
  __shared__ __align__(16) short Bs[2][BN * 32];
  __shared__ float wred[4][2][32];              // STATS scratch (1 KB)

  const int tid  = threadIdx.x;
  const int lane = tid & 63;
  const int wv   = tid >> 6;
  const int wr   = wv >> 1;
  const int wc   = wv & 1;

  // ---- bijective XCD swizzle of the flattened block id (m204) ----
  const int gx = gridDim.x, gy = gridDim.y;
  const int nwg = gx * gy * gridDim.z;
  const int lin = blockIdx.x + gx * (blockIdx.y + gy * blockIdx.z);
  const int q = nwg >> 3, r = nwg & 7;
  const int xcd = lin & 7, sub = lin >> 3;
  const int work = (xcd < r ? xcd * (q + 1) : r * (q + 1) + (xcd - r) * q) + sub;
  const int bx = work % gx;
  const int by = (work / gx) % gy;
  const int bz = work / (gx * gy);

  const int mbase = bx * BM;
  const int nbase = by * BN;
  const int kstart = PARTIAL ? bz * Kloc : 0;

  // ---- staging: chunk = row (c>>2), 16B sub (c&3), swizzled source sub ----
  const int srow = tid >> 2;                       // 0..63
  const int sb   = (((tid & 3) ^ ((srow ^ (srow >> 2)) & 3))) * 8;
  const unsigned short* agp[AI];
  const unsigned short* bgp[BI];
#pragma unroll
  for (int i = 0; i < AI; ++i) {
    int ma = min(mbase + i * 64 + srow, M - 1);
    int b0 = ma / To, t0 = ma % To;
    agp[i] = xin + (size_t)b0 * b_stride + row_off
             + (size_t)t0 * row_t_stride + sb + kstart;
  }
#pragma unroll
  for (int i = 0; i < BI; ++i)
    bgp[i] = Wr + (size_t)(nbase + i * 64 + srow) * Ktot + sb + kstart;

  f32x4 acc[FM][FN] = {};
  const int nsteps = Kloc >> 5;

#define STAGE(buf, k0)                                                \
  do {                                                                \
    _Pragma("unroll")                                                 \
    for (int i = 0; i < AI; ++i)                                      \
      GLOAD_LDS16(agp[i] + (k0), &As[buf][i * 2048 + wv * 512]);      \
    _Pragma("unroll")                                                 \
    for (int i = 0; i < BI; ++i)                                      \
      GLOAD_LDS16(bgp[i] + (k0), &Bs[buf][i * 2048 + wv * 512]);      \
  } while (0)

  STAGE(0, 0);
  __syncthreads();

  const int l15   = lane & 15;
  const int rsw   = (l15 ^ (l15 >> 2)) & 3;
  const int chunk = ((lane >> 4) ^ rsw) * 8;
  const int a_off = (wr * (BM / 2) + l15) * 32 + chunk;
  const int b_off = (wc * (BN / 2) + l15) * 32 + chunk;

  for (int s = 0; s < nsteps; ++s) {
    const int nb = s & 1;
    if (s + 1 < nsteps) STAGE(nb ^ 1, (s + 1) * 32);

    const short* Ab = &As[nb][a_off];
    const short* Bb = &Bs[nb][b_off];
    short8 af[FM], bf[FN];
#pragma unroll
    for (int f = 0; f < FM; ++f)
      af[f] = *reinterpret_cast<const short8*>(Ab + f * 512);
#pragma unroll
    for (int f = 0; f < FN; ++f)
      bf[f] = *reinterpret_cast<const short8*>(Bb + f * 512);
#pragma unroll
    for (int fm = 0; fm < FM; ++fm)
#pragma unroll
      for (int fn = 0; fn < FN; ++fn)
        acc[fm][fn] = __builtin_amdgcn_mfma_f32_16x16x32_bf16(af[fm], bf[fn], acc[fm][fn], 0, 0, 0);

    __syncthreads();
  }
#undef STAGE

  // ---- epilogue: C/D map col=lane&15, row=4*(lane>>4)+reg ----
  const int cl = lane & 15, rh = lane >> 4;
  float ls[FN], lq[FN];
#pragma unroll
  for (int f = 0; f < FN; ++f) { ls[f] = 0.f; lq[f] = 0.f; }
#pragma unroll
  for (int fm = 0; fm < FM; ++fm) {
#pragma unroll
    for (int fn = 0; fn < FN; ++fn) {
      int col = nbase + wc * (BN / 2) + fn * 16 + cl;
      float bv = BIAS ? bias[col] : 0.f;
      f32x4 v = acc[fm][fn];
#pragma unroll
      for (int rr = 0; rr < 4; ++rr) {
        int m = mbase + wr * (BM / 2) + fm * 16 + rh * 4 + rr;
        if (m < M) {
          if (PARTIAL) {
            float* pout = (float*)out + (size_t)bz * ((size_t)M * ldout);
            pout[(size_t)m * ldout + col] = v[rr];
          } else {
            int b = m / To, to = m % To;
            float x = v[rr] + bv;
            if (RELU) x = fmaxf(x, 0.f);
            size_t oi = ((size_t)b * TP_ + t_off_out + to) * (size_t)ldout + col;
            if (OUT_BF16) ((unsigned short*)out)[oi] = f2bf(x);
            else          ((float*)out)[oi] = x;
            if (STATS) { ls[fn] += x; lq[fn] += x * x; }
          }
        }
      }
    }
  }

  if (STATS) {   // deterministic per-block column stats (BM=BN=64 path)
#pragma unroll
    for (int fn = 0; fn < FN; ++fn) {
      float s = ls[fn], qq = lq[fn];
      s  += __shfl_xor(s, 16, 64);  qq += __shfl_xor(qq, 16, 64);
      s  += __shfl_xor(s, 32, 64);  qq += __shfl_xor(qq, 32, 64);
      if (rh == 0) { wred[wv][0][fn * 16 + cl] = s; wred[wv][1][fn * 16 + cl] = qq; }
    }
    __syncthreads();
    if (tid < 64) {
      int wc2 = tid >> 5, cl2 = tid & 31;
      float s  = wred[wc2][0][cl2] + wred[wc2 + 2][0][cl2];
      float qq = wred[wc2][1][cl2] + wred[wc2 + 2][1][cl2];
      int chan = nbase + wc2 * 32 + cl2;
      spart[(size_t)bx * 1024 + chan]       = s;
      spart[(size_t)bx * 1024 + 512 + chan] = qq;
    }
  }
}

// ---------------------------------------------------------------------------
// K-split reduce: sum S partials [S][M][512], +bias, relu, bf16, scatter.
// ---------------------------------------------------------------------------
template<int S>
__global__ void reduce_conv_k(const float* __restrict__ part, const float* __restrict__ bias,
                              unsigned short* __restrict__ outb,
                              int M, int To, int t_off_out) {
  int idx = blockIdx.x * 256 + threadIdx.x;      // over M*128 float4s
  int m = idx >> 7, n4 = idx & 127;
  if (m >= M) return;
  size_t off = (size_t)m * 512 + n4 * 4;
  float4 a = *reinterpret_cast<const float4*>(part + off);
#pragma unroll
  for (int s = 1; s < S; ++s) {
    float4 b = *reinterpret_cast<const float4*>(part + (size_t)s * M * 512 + off);
    a.x += b.x; a.y += b.y; a.z += b.z; a.w += b.w;
  }
  float4 bv = *reinterpret_cast<const float4*>(bias + n4 * 4);
  a.x = fmaxf(a.x + bv.x, 0.f);
  a.y = fmaxf(a.y + bv.y, 0.f);
  a.z = fmaxf(a.z + bv.z, 0.f);
  a.w = fmaxf(a.w + bv.w, 0.f);
  int b_ = m / To, to = m % To;
  ushort4_t h = { f2bf(a.x), f2bf(a.y), f2bf(a.z), f2bf(a.w) };
  reinterpret_cast<ushort4_t*>(outb + ((size_t)b_ * TP_ + t_off_out + to) * 512)[n4] = h;
}

// ---------------------------------------------------------------------------
// Normalize v2 in place (fp32), emit bf16 copy + row norms vn.
// ---------------------------------------------------------------------------
__global__ void v2_norm_vn_k(float* __restrict__ v2, const float* __restrict__ ms,
                             unsigned short* __restrict__ v2bf, float* __restrict__ vn) {
  int r = blockIdx.x, t = threadIdx.x;
  float* row = v2 + (size_t)r * DJ_;
  unsigned short* brow = v2bf + (size_t)r * DJ_;
  float ss = 0.f;
#pragma unroll
  for (int h = 0; h < 2; ++h) {
    int c4 = t + h * 64;
    float4 v = reinterpret_cast<float4*>(row)[c4];
    int c = c4 * 4;
    v.x = (v.x - ms[c+0]) * ms[DJ_+c+0];
    v.y = (v.y - ms[c+1]) * ms[DJ_+c+1];
    v.z = (v.z - ms[c+2]) * ms[DJ_+c+2];
    v.w = (v.w - ms[c+3]) * ms[DJ_+c+3];
    reinterpret_cast<float4*>(row)[c4] = v;
    ushort4_t h4 = { f2bf(v.x), f2bf(v.y), f2bf(v.z), f2bf(v.w) };
    reinterpret_cast<ushort4_t*>(brow)[c4] = h4;
    ss += v.x*v.x + v.y*v.y + v.z*v.z + v.w*v.w;
  }
#pragma unroll
  for (int o = 32; o; o >>= 1) ss += __shfl_down(ss, o, 64);
  if (t == 0) vn[r] = sqrtf(ss);
}

// ---------------------------------------------------------------------------
// sim kernel
// ---------------------------------------------------------------------------
__global__ __launch_bounds__(256) void sim_k(
    const float* __restrict__ A, const float* __restrict__ G,
    const float* __restrict__ vn, const float* __restrict__ wmask,
    float* __restrict__ pos, float* __restrict__ scores) {
  int j = blockIdx.x, i = blockIdx.y;
  __shared__ float sG[400];
  __shared__ float sm[20];
  __shared__ float red[4];
  int tid = threadIdx.x;
  for (int p = tid; p < 400; p += 256) sG[p] = G[i * 400 + p];
  if (tid < 20) sm[tid] = wmask[i * 20 + tid];
  __syncthreads();

  float simv = -1e30f;
  if (tid < TP_) {
    const float* ar = A + ((size_t)j * TP_ + tid) * 640 + i * 20;
    float a[20], p[20];
    float mx = -1e30f;
#pragma unroll
    for (int l = 0; l < 20; ++l) {
      a[l] = ar[l];
      float lg = (sm[l] > 0.5f) ? LAM_ * a[l] : -1e9f;
      p[l] = lg;
      mx = fmaxf(mx, lg);
    }
    float Z = 0.f;
#pragma unroll
    for (int l = 0; l < 20; ++l) { p[l] = __expf(p[l] - mx); Z += p[l]; }
    float invZ = 1.f / Z, num = 0.f;
#pragma unroll
    for (int l = 0; l < 20; ++l) { p[l] *= invZ; num += p[l] * a[l]; }
    float q2 = 0.f;
#pragma unroll
    for (int l = 0; l < 20; ++l) {
      float gi = 0.f;
#pragma unroll
      for (int l2 = 0; l2 < 20; ++l2) gi += sG[l * 20 + l2] * p[l2];
      q2 += p[l] * gi;
    }
    float vnv = fmaxf(vn[(size_t)j * TP_ + tid], 1e-8f);
    float vsnv = fmaxf(sqrtf(q2), 1e-8f);
    simv = num / (vnv * vsnv);
    if (i == j) pos[i * TP_ + tid] = simv;
  }
  float mv = simv;
#pragma unroll
  for (int o = 32; o; o >>= 1) mv = fmaxf(mv, __shfl_down(mv, o, 64));
  if ((tid & 63) == 0) red[tid >> 6] = mv;
  __syncthreads();
  if (tid == 0)
    scores[i * 32 + j] = fmaxf(fmaxf(red[0], red[1]), fmaxf(red[2], red[3]));
}

// margin ranking loss over scores[32][32]
__global__ void loss_k(const float* __restrict__ scores, float* __restrict__ out) {
  __shared__ float red[16];
  int tid = threadIdx.x;
  int i = tid >> 5, j = tid & 31;
  float s = scores[tid];
  float dgi = scores[i * 32 + i], dgj = scores[j * 32 + j];
  float c = 0.f;
  if (i != j)
    c = fmaxf(0.f, MARGIN_ + s - dgi) + fmaxf(0.f, MARGIN_ + s - dgj);
#pragma unroll
  for (int o = 32; o; o >>= 1) c += __shfl_down(c, o, 64);
  if ((tid & 63) == 0) red[tid >> 6] = c;
  __syncthreads();
  if (tid == 0) {
    float t = 0.f;
    for (int w = 0; w < 16; ++w) t += red[w];
    out[0] = t / 32.f;
  }
}

// ---------------------------------------------------------------------------
extern "C" void kernel_launch(void* const* d_in, const int* in_sizes, int n_in,
                              void* d_out, int out_size, void* d_ws, size_t ws_size,
                              hipStream_t stream) {
  const float* video = (const float*)d_in[0];
  const float* words = (const float*)d_in[1];
  const float* wmask = (const float*)d_in[2];
  const float* c0w = (const float*)d_in[3];
  const float* c0b = (const float*)d_in[4];
  const float* c1w = (const float*)d_in[5];
  const float* c1b = (const float*)d_in[6];
  const float* c2w = (const float*)d_in[7];
  const float* c2b = (const float*)d_in[8];
  const float* pww = (const float*)d_in[9];
  const float* pwb = (const float*)d_in[10];
  float* out = (float*)d_out;
  float* ws  = (float*)d_ws;

  // ---- workspace layout (float units) ----
  // Pbuf overlay: conv K-split partials (launches 4-9) share space with
  // arrays dead before conv0 (vpart/vms/wpart/wms) or written after (v2..).
  // wbnb/G/vn/scores live across the conv tower -> OUTSIDE the overlay.
  float*          W0r    = ws;                       // 1048576
  float*          W1r    = W0r + 1048576;            // 524288
  float*          W2r    = W1r + 524288;             // 524288
  float*          Wpw    = W2r + 524288;             // 131072  (end 2228224)
  float*          AMvbf  = Wpw + 131072;             // 4485120 (vbf | Amat)
  float*          vcatb  = AMvbf + 4485120;          // 1794048 (bf16 vcat)
  float*          Pbuf   = vcatb + 1794048;          // 8323072 overlay:
  float*          v2     = Pbuf;                     //   3588096
  float*          v2bfp  = v2 + 3588096;             //   1794048
  float*          v2part = v2bfp + 1794048;          //   112640 (110 groups)
  float*          v2ms   = v2part + 112640;          //   1024
  float*          vpart  = v2ms + 1024;              //   1048576
  float*          vms    = vpart + 1048576;          //   2048
  float*          wpart  = vms + 2048;               //   81920
  float*          wms    = wpart + 81920;            //   1024  (fits 8323072)
  float*          endPb  = Pbuf + 8323072;
  float*          wbnbp  = endPb;                    // 163840 f (bf16 327680)  [R8 BUG: was 81920]
  float*          G      = wbnbp + 163840;           // 12800
  float*          vn     = G + 12800;                // 7008
  float*          scores = vn + 7008;                // 1024   (~68.1 MB total)

  unsigned short* W0     = (unsigned short*)W0r;
  unsigned short* W1     = (unsigned short*)W1r;
  unsigned short* W2     = (unsigned short*)W2r;
  unsigned short* Wp     = (unsigned short*)Wpw;
  unsigned short* vbf    = (unsigned short*)AMvbf;
  float*          Amat   = AMvbf;
  unsigned short* vcb    = (unsigned short*)vcatb;
  unsigned short* v2bf   = (unsigned short*)v2bfp;
  unsigned short* wbnb   = (unsigned short*)wbnbp;

  // 1: weight reorder + video stats1 + words stats1
  prep_k<<<4904, 256, 0, stream>>>(c0w, c1w, c2w, pww, W0, W1, W2, Wp,
                                   video, vpart, words, wpart);
  // 2: video stats2 + words stats2
  stats2c_k<<<12, 256, 0, stream>>>(vpart, vms, wpart, wms);
  // 3: video BN cast + words BN->bf16 + Gram
  cast_wgram_k<<<8224, 256, 0, stream>>>(video, vms, vbf, words, wms, wbnb, G);

  // ---- conv tower, K-split for occupancy, fp32 partials -> reduce ----
  // 4/5: conv0  M=4064, K=4096 -> 4x1024.  64x128 tile, (64,4,4)=1024 blk
  gemm_k<64, 128, false, false, false, true, false><<<dim3(64, 4, 4), 256, 0, stream>>>(
      vbf, W0, nullptr, Pbuf, nullptr, 262144, 0, 2048, T0_, 32 * T0_, 0, 512, 4096, 1024);
  reduce_conv_k<4><<<2032, 256, 0, stream>>>(Pbuf, c0b, vcb, 32 * T0_, T0_, 0);
  // 6/7: conv1  M=1984, K=2048 -> 8x256.  64x128 tile, (31,4,8)=992 blk
  gemm_k<64, 128, false, false, false, true, false><<<dim3(31, 4, 8), 256, 0, stream>>>(
      vcb, W1, nullptr, Pbuf, nullptr, 112128, 0, 1024, T1_, 32 * T1_, 0, 512, 2048, 256);
  reduce_conv_k<8><<<992, 256, 0, stream>>>(Pbuf, c1b, vcb, 32 * T1_, T1_, T0_);
  // 8/9: conv2  M=960, K=2048 -> 8x256.  64x64 tile, (15,8,8)=960 blk
  gemm_k<64, 64, false, false, false, true, false><<<dim3(15, 8, 8), 256, 0, stream>>>(
      vcb, W2, nullptr, Pbuf, nullptr, 112128, 65024, 1024, T2_, 32 * T2_, 0, 512, 2048, 256);
  reduce_conv_k<8><<<480, 256, 0, stream>>>(Pbuf, c2b, vcb, 32 * T2_, T2_, T0_ + T1_);

  // 10: pointwise conv -> v2 fp32, with fused BN-stats stage 1 epilogue
  gemm_k<64, 64, false, true, false, false, true><<<dim3(110, 8), 256, 0, stream>>>(
      vcb, Wp, pwb, v2, v2part, 112128, 0, 512, TP_, 32 * TP_, 0, 512, 512, 512);

  // 11: v2 stats2 ; 12: v2 BN apply + bf16 + row norms
  stats2_k<<<4, 256, 0, stream>>>(v2part, v2ms, 512, 110, 1.f / 7008.f);
  v2_norm_vn_k<<<7008, 64, 0, stream>>>(v2, v2ms, v2bf, vn);

  // 13: A[(j,t)][(i,l)] = v . w  (M=7008, N=640, K=512) -> Amat (overlays vbf)
  gemm_k<64, 64, false, false, false, false, false><<<dim3(110, 10), 256, 0, stream>>>(
      v2bf, wbnb, nullptr, Amat, nullptr, 112128, 0, 512, TP_, 32 * TP_, 0, 640, 512, 512);

  // 14/15: fused softmax/cosine/scores/pos_map ; margin loss
  sim_k<<<dim3(32, 32), 256, 0, stream>>>(Amat, G, vn, wmask, out + 1, scores);
  loss_k<<<1, 1024, 0, stream>>>(scores, out);
}